// Round 23
// baseline (72.686 us; speedup 1.0000x reference)
//
#include <hip/hip_runtime.h>
#include <math.h>

#define BB 4
#define CC 64
#define HH 128
#define WW 128
#define HWP 16384

typedef _Float16 h2 __attribute__((ext_vector_type(2)));
typedef _Float16 h4 __attribute__((ext_vector_type(4)));
typedef __fp16  p2 __attribute__((ext_vector_type(2)));   // cvt_pkrtz's return type
typedef float f32x4 __attribute__((ext_vector_type(4)));
union HU { unsigned u; h2 h; p2 p; };
union U2H { uint2 u; h4 h; };
static __device__ __forceinline__ h2 u2h(unsigned x){ HU v; v.u = x; return v.h; }
static __device__ __forceinline__ unsigned h2u(h2 x){ HU v; v.h = x; return v.u; }
static __device__ __forceinline__ unsigned pk2u(float a, float b){
    HU v; v.p = __builtin_amdgcn_cvt_pkrtz(a, b); return v.u;
}

// ---------------- kTm: merged kT (blocks 0..511) + k0 weight-pack (512..655).
__global__ __launch_bounds__(256) void kTm(
    const float* __restrict__ f1, const float* __restrict__ f3,
    const float* __restrict__ ow, const float* __restrict__ mw,
    unsigned* __restrict__ f13t, unsigned* __restrict__ wmf,
    unsigned* __restrict__ wof)
{
    __shared__ float lt[64*129];
    int t = threadIdx.x;
    if (blockIdx.x < 512) {
        int b = blockIdx.x >> 7, y = blockIdx.x & 127;
        unsigned* dst = f13t + ((size_t)((b << 14) + (y << 7)))*64;
        for (int half = 0; half < 2; ++half) {
            const float* src = (half == 0 ? f1 : f3) + (((size_t)b*64) << 14) + (y << 7);
#pragma unroll 4
            for (int i = 0; i < 32; ++i) {
                int idx = i*256 + t; int c = idx >> 7, x = idx & 127;
                lt[c*129 + x] = src[(c << 14) + x];
            }
            __syncthreads();
#pragma unroll 4
            for (int i = 0; i < 16; ++i) {
                int idx = i*256 + t; int x = idx >> 5, cp = idx & 31;
                dst[x*64 + half*32 + cp] = pk2u(lt[(2*cp)*129 + x], lt[(2*cp+1)*129 + x]);
            }
            __syncthreads();
        }
        return;
    }
    int i = (blockIdx.x - 512)*256 + t;
    if (i < 18432) {                           // wmf: 4*64*36*2
        int j   = i & 1;
        int t2  = i >> 1;
        int kb  = t2 % 36;
        int rl  = t2 / 36;
        int l   = rl & 63;
        int r   = rl >> 6;
        int row = l & 15, ksel = l >> 4;
        int och = r*16 + row;
        int P   = kb*8 + ksel*2 + j;           // 0..287
        int kt  = P >> 5;
        int cp  = P & 31;
        float lo = mw[och*576 + (2*cp    )*9 + kt];
        float hi = mw[och*576 + (2*cp + 1)*9 + kt];
        wmf[i] = pk2u(lo, hi);
    } else if (i < 36864) {                    // wof: 2*64*72*2
        int idx = i - 18432;
        int j   = idx & 1;
        int t2  = idx >> 1;
        int kb  = t2 % 72;
        int rl  = t2 / 72;
        int l   = rl & 63;
        int mt  = rl >> 6;
        int row = l & 15, ksel = l >> 4;
        int och = mt*16 + row;
        int P   = kb*8 + ksel*2 + j;           // 0..575
        int kt  = P >> 6;                      // tap 0..8
        int cp  = P & 63;                      // concat pair
        unsigned v = 0;
        if (och < 27) {
            float lo = ow[(och*128 + 2*cp    )*9 + kt];
            float hi = ow[(och*128 + 2*cp + 1)*9 + kt];
            v = pk2u(lo, hi);
        }
        wof[idx] = v;
    }
}

// ---------------- K1: offset conv via MFMA, y-PAIR blocks (R21, unchanged).
__global__ __launch_bounds__(256) void k1_offset_conv(
    const unsigned* __restrict__ f13t, const unsigned* __restrict__ wof,
    const float* __restrict__ ob, float* __restrict__ om)
{
    extern __shared__ unsigned tile[];   // [4 slabs][34][68] = 36,992 B

    int blk0 = blockIdx.x;
    int blk  = ((blk0 & 7) << 7) | (blk0 >> 3);   // bijective (1024 % 8 == 0)
    int xq = blk & 3;
    int yp = (blk >> 2) & 63;
    int b  = blk >> 8;
    int y0r = yp << 1;

    int tid  = threadIdx.x;
    int lane = tid & 63;
    int wv   = tid >> 6;
    int mt   = wv >> 1;          // M-tile (out-ch 16*mt..)
    int ys   = wv & 1;           // row of pair
    int row  = lane & 15;
    int ksel = lane >> 4;

    // stage 4 slabs: rows y0r-1 .. y0r+2
#pragma unroll 1
    for (int s = 0; s < 4; ++s) {
        int yy = y0r + s - 1;
        bool yok = (unsigned)yy < (unsigned)HH;
        unsigned* ts = tile + s*2312;
        for (int i = tid; i < 544; i += 256) {
            int px34 = i >> 4, q = i & 15;
            int gxp = xq*32 - 1 + px34;
            uint4 v = make_uint4(0u, 0u, 0u, 0u);
            if (yok && (unsigned)gxp < (unsigned)WW)
                v = *(const uint4*)&f13t[(((size_t)(b*128 + yy))*128 + gxp)*64 + q*4];
            *(uint4*)&ts[px34*68 + q*4] = v;
        }
    }
    __syncthreads();

    f32x4 acc0 = {0.f, 0.f, 0.f, 0.f};
    f32x4 acc1 = {0.f, 0.f, 0.f, 0.f};
    const unsigned* wbase = wof + (size_t)(mt*64 + lane)*144;

#pragma unroll 1
    for (int dy = 0; dy < 3; ++dy) {
        const unsigned* ts = tile + (ys + dy)*2312;
#pragma unroll
        for (int hf = 0; hf < 2; ++hf) {
            uint4 wq[6];
#pragma unroll
            for (int m = 0; m < 6; ++m)
                wq[m] = *(const uint4*)&wbase[dy*48 + hf*24 + m*4];
#pragma unroll
            for (int kl = 0; kl < 12; ++kl) {
                int Pl  = (hf*12 + kl)*8 + ksel*2;
                int ktl = Pl >> 6;
                int cp  = Pl & 63;
                U2H wa;
                uint4 q = wq[kl >> 1];
                if (kl & 1) { wa.u.x = q.z; wa.u.y = q.w; }
                else        { wa.u.x = q.x; wa.u.y = q.y; }
                U2H b0, b1;
                b0.u = *(const uint2*)&ts[(row + ktl)*68 + cp];
                b1.u = *(const uint2*)&ts[(16 + row + ktl)*68 + cp];
                acc0 = __builtin_amdgcn_mfma_f32_16x16x16f16(wa.h, b0.h, acc0, 0, 0, 0);
                acc1 = __builtin_amdgcn_mfma_f32_16x16x16f16(wa.h, b1.h, acc1, 0, 0, 0);
            }
        }
    }

    int y  = y0r + ys;
    int gx0 = xq*32 + row;
#pragma unroll
    for (int rI = 0; rI < 4; ++rI) {
        int och = mt*16 + ksel*4 + rI;
        if (och < 27) {
            float v0 = acc0[rI] + ob[och];
            float v1 = acc1[rI] + ob[och];
            if (och >= 18) {
                v0 = 1.f / (1.f + __expf(-v0));   // mask sigmoid
                v1 = 1.f / (1.f + __expf(-v1));
            }
            int base = ((b*27 + och) << 14) + (y << 7) + gx0;
            om[base]      = v0;
            om[base + 16] = v1;
        }
    }
}

// ---------------- K2: deformable conv, half-row blocks, 512 THREADS (8 waves).
// Same geometry/addresses as R22; 2x waves for TA/latency hiding.
// Wave wv = (och-tile ot = wv&3, px-half ph = wv>>2); 2 accs per wave.
// LDS: params 1728 + sl[64][100] = 32,512 B.
__global__ __launch_bounds__(512) void k2_deform(
    const unsigned* __restrict__ f13t, const unsigned* __restrict__ wmf,
    const float* __restrict__ om, unsigned* __restrict__ alignedh,
    float* __restrict__ part)
{
    extern __shared__ unsigned lds[];
    unsigned* pl_a = lds;            // [9][64] addr|dx<<14|dy<<15
    unsigned* pl_w = lds + 576;      // [9][64] x uint2
    unsigned* sl   = lds + 1728;     // [64 px][100] permuted half2 samples

    int blk0 = blockIdx.x;
    int blk  = ((blk0 & 7) << 7) | (blk0 >> 3);   // bijective (1024 % 8 == 0)
    int xh = blk & 1;
    int y  = (blk >> 1) & 127;
    int b  = blk >> 8;

    int tid  = threadIdx.x;
    int lane = tid & 63;
    int wv   = tid >> 6;         // 0..7
    int ot   = wv & 3;           // och tile
    int ph   = wv >> 2;          // px half (tiles 2ph, 2ph+1)
    int row  = lane & 15;
    int ksel = (lane >> 4) & 3;
    int cg   = tid & 7;          // phase-A channel group (4 pairs)
    int grp  = tid >> 3;         // phase-A item group 0..63
    int pwb  = ((cg >> 2) << 4) | ((cg & 1) << 3) | (((cg >> 1) & 1) << 1);

    const float* omb = om + ((b*27) << 14) + (y << 7);
    const unsigned* ftb = f13t + (((size_t)b) << 20);

    // ---- param pre-phase: 576 items (k, px in half-row)
    for (int i = tid; i < 576; i += 512) {
        int k = i >> 6, lpx = i & 63;
        int gxp = xh*64 + lpx;
        float off0 = omb[((2*k)   << 14) + gxp];
        float off1 = omb[((2*k+1) << 14) + gxp];
        float mk   = omb[((18+k)  << 14) + gxp];   // sigmoided in K1

        float pyf = (float)y   + (float)(k/3) - 1.f + off0;
        float pxg = (float)gxp + (float)(k%3) - 1.f + off1;
        float fy = floorf(pyf), fx = floorf(pxg);
        int y0 = (int)fy, x0 = (int)fx;
        float wy = pyf - fy, wx = pxg - fx;
        float oy = 1.f - wy, ox = 1.f - wx;
        bool yv0 = (unsigned)y0     < (unsigned)HH;
        bool yv1 = (unsigned)(y0+1) < (unsigned)HH;
        bool xv0 = (unsigned)x0     < (unsigned)WW;
        bool xv1 = (unsigned)(x0+1) < (unsigned)WW;
        int y0c = min(max(y0, 0), 127);
        int x0c = min(max(x0, 0), 127);
        int dy = min(max(y0+1, 0), 127) - y0c;   // 0 or 1
        int dx = min(max(x0+1, 0), 127) - x0c;   // 0 or 1
        unsigned a = (unsigned)((y0c << 7) + x0c) | ((unsigned)dx << 14) | ((unsigned)dy << 15);
        float w00 = (yv0 && xv0) ? oy*ox*mk : 0.f;
        float w01 = (yv0 && xv1) ? oy*wx*mk : 0.f;
        float w10 = (yv1 && xv0) ? wy*ox*mk : 0.f;
        float w11 = (yv1 && xv1) ? wy*wx*mk : 0.f;
        pl_a[i] = a;
        pl_w[i*2]     = pk2u(w00, w01);
        pl_w[i*2 + 1] = pk2u(w10, w11);
    }
    __syncthreads();

    f32x4 accA = {0.f,0.f,0.f,0.f};   // px-tile 2ph   (px = 32ph + row)
    f32x4 accB = {0.f,0.f,0.f,0.f};   // px-tile 2ph+1 (px = 32ph + 16 + row)

    const unsigned* wbase = wmf + (ot*64 + lane)*72;

#pragma unroll 1
    for (int th = 0; th < 3; ++th) {
        uint4 wq[6];
#pragma unroll
        for (int m = 0; m < 6; ++m)
            wq[m] = *(const uint4*)&wbase[th*24 + m*4];

        // phase A: 192 items (ktl,px); 64 groups of 8 lanes, 3 items/group
#pragma unroll
        for (int it = 0; it < 3; ++it) {
            int item = it*64 + grp;            // 0..191
            int ktl  = item >> 6;              // 0..2
            int px   = item & 63;
            int k    = th*3 + ktl;
            int pidx = k*64 + px;
            unsigned a = pl_a[pidx];
            uint2 wpk = *(const uint2*)&pl_w[pidx*2];
            int i00 = (int)(a & 0x3FFFu);
            int dx  = (int)((a >> 14) & 1u);
            int i10 = i00 + (((int)(a >> 15) & 1) << 7);
            h2 hw01 = u2h(wpk.x);
            h2 hw23 = u2h(wpk.y);
            h2 w00d = {hw01.x, hw01.x}, w01d = {hw01.y, hw01.y};
            h2 w10d = {hw23.x, hw23.x}, w11d = {hw23.y, hw23.y};

            uint4 t00 = *(const uint4*)&ftb[(size_t)(i00     )*64 + 4*cg];
            uint4 t01 = *(const uint4*)&ftb[(size_t)(i00 + dx)*64 + 4*cg];
            uint4 t10 = *(const uint4*)&ftb[(size_t)(i10     )*64 + 4*cg];
            uint4 t11 = *(const uint4*)&ftb[(size_t)(i10 + dx)*64 + 4*cg];

            h2 v0 = u2h(t00.x)*w00d + u2h(t01.x)*w01d + u2h(t10.x)*w10d + u2h(t11.x)*w11d;
            h2 v1 = u2h(t00.y)*w00d + u2h(t01.y)*w01d + u2h(t10.y)*w10d + u2h(t11.y)*w11d;
            h2 v2 = u2h(t00.z)*w00d + u2h(t01.z)*w01d + u2h(t10.z)*w10d + u2h(t11.z)*w11d;
            h2 v3 = u2h(t00.w)*w00d + u2h(t01.w)*w01d + u2h(t10.w)*w10d + u2h(t11.w)*w11d;

            int bs = px*100 + ktl*32 + pwb;
            *(uint2*)&sl[bs]     = make_uint2(h2u(v0), h2u(v1));
            *(uint2*)&sl[bs + 4] = make_uint2(h2u(v2), h2u(v3));
        }
        __syncthreads();

        // phase B: 6 double-K-blocks x 2 px-tiles, ds_read_b128
        const unsigned* bpA = &sl[(32*ph + row     )*100 + ksel*4];
        const unsigned* bpB = &sl[(32*ph + 16 + row)*100 + ksel*4];
#pragma unroll
        for (int m = 0; m < 6; ++m) {
            uint4 bvA = *(const uint4*)&bpA[m*16];
            uint4 bvB = *(const uint4*)&bpB[m*16];
            U2H waA, waB, sa, sb;
            waA.u.x = wq[m].x; waA.u.y = wq[m].y;
            waB.u.x = wq[m].z; waB.u.y = wq[m].w;
            sa.u.x = bvA.x; sa.u.y = bvA.y;
            sb.u.x = bvA.z; sb.u.y = bvA.w;
            accA = __builtin_amdgcn_mfma_f32_16x16x16f16(waA.h, sa.h, accA, 0, 0, 0);
            accA = __builtin_amdgcn_mfma_f32_16x16x16f16(waB.h, sb.h, accA, 0, 0, 0);
            sa.u.x = bvB.x; sa.u.y = bvB.y;
            sb.u.x = bvB.z; sb.u.y = bvB.w;
            accB = __builtin_amdgcn_mfma_f32_16x16x16f16(waA.h, sa.h, accB, 0, 0, 0);
            accB = __builtin_amdgcn_mfma_f32_16x16x16f16(waB.h, sb.h, accB, 0, 0, 0);
        }
        __syncthreads();
    }

    // write aligned (packed f16 pairs) + per-block stats partials.
    // sred: two 128-float slots (one per px-half), summed at the end.
    float* sred = (float*)lds;   // reuse (safe: past last barrier)
#pragma unroll
    for (int rI = 0; rI < 4; ++rI) {
        int och = ot*16 + ksel*4 + rI;
        float v0 = accA[rI], v1 = accB[rI];
        int ai = (((b*CC + och) << 13)) + (y << 6) + row;
        alignedh[ai + ((2*xh + ph) << 4)] = pk2u(v0, v1);
        float s  = v0 + v1;
        float sq = v0*v0 + v1*v1;
#pragma unroll
        for (int off = 1; off < 16; off <<= 1) {
            s  += __shfl_xor(s,  off, 64);
            sq += __shfl_xor(sq, off, 64);
        }
        if (row == 0) {
            sred[ph*128 + och]      = s;
            sred[ph*128 + 64 + och] = sq;
        }
    }
    __syncthreads();
    for (int i = tid; i < 128; i += 512)
        part[(size_t)blk*128 + i] = sred[i] + sred[128 + i];
}

// ---------------- K3b: reduce 1024 per-block partials -> stats[128]
__global__ __launch_bounds__(256) void k3b_reduce(
    const float* __restrict__ part, float* __restrict__ stats)
{
    int i = blockIdx.x;           // 0..127
    int tid = threadIdx.x;
    float s = 0.f;
    for (int j = tid; j < 1024; j += 256) s += part[(size_t)j*128 + i];
    for (int off = 32; off > 0; off >>= 1) s += __shfl_down(s, off, 64);
    __shared__ float rs[4];
    int w = tid >> 6;
    if ((tid & 63) == 0) rs[w] = s;
    __syncthreads();
    if (tid == 0) stats[i] = rs[0] + rs[1] + rs[2] + rs[3];
}

// ---------------- K4: normalize + affine, f16-packed input -> f32 out.
__global__ __launch_bounds__(256) void k4_norm(
    const unsigned* __restrict__ alignedh, const float* __restrict__ stats,
    const float* __restrict__ gamma, const float* __restrict__ beta,
    float* __restrict__ out)
{
    const float invN = 1.f / 65536.f;
    int i4 = blockIdx.x*256 + threadIdx.x;     // 0..524287
    int u  = i4 << 2;
    int c  = (u >> 13) & 63;
    int lx = u & 15;
    int xq = (u >> 4) & 3;
    int y  = (u >> 6) & 127;
    int bc = u >> 13;                          // b*64 + c

    float mean = stats[c] * invN;
    float var  = stats[64 + c] * invN - mean*mean;
    float sc = gamma[c] * rsqrtf(var + 1e-5f);
    float sh = beta[c] - mean*sc;

    uint4 v = *(const uint4*)&alignedh[u];
    h2 p0 = u2h(v.x), p1 = u2h(v.y), p2 = u2h(v.z), p3 = u2h(v.w);
    float4 lo = make_float4((float)p0.x*sc + sh, (float)p1.x*sc + sh,
                            (float)p2.x*sc + sh, (float)p3.x*sc + sh);
    float4 hi = make_float4((float)p0.y*sc + sh, (float)p1.y*sc + sh,
                            (float)p2.y*sc + sh, (float)p3.y*sc + sh);
    int ob = (bc << 14) + (y << 7) + xq*32 + lx;
    *(float4*)&out[ob]      = lo;
    *(float4*)&out[ob + 16] = hi;
}

extern "C" void kernel_launch(void* const* d_in, const int* in_sizes, int n_in,
                              void* d_out, int out_size, void* d_ws, size_t ws_size,
                              hipStream_t stream)
{
    const float* f1    = (const float*)d_in[0];
    const float* f3    = (const float*)d_in[1];
    const float* ow    = (const float*)d_in[2];
    const float* ob    = (const float*)d_in[3];
    const float* mw    = (const float*)d_in[4];
    const float* gamma = (const float*)d_in[5];
    const float* beta  = (const float*)d_in[6];
    float* out = (float*)d_out;

    float* om     = (float*)d_ws;                 // [4][27][128][128] = 7,077,888 B
    float* stats  = om + 4*27*HWP;                // [128] floats (512 reserved)
    unsigned* wmf = (unsigned*)(stats + 512);     // 18432 u32
    unsigned* wof = wmf + 18432;                  // 18432 u32
    unsigned* f13t = wof + 18432;                 // [4][128][128][64] u32 = 16 MB
    float* part   = (float*)(f13t + 4*HWP*64);    // [1024][128] floats
    unsigned* alignedh = (unsigned*)(part + 2048*128);  // [4][64][128][64] u32 = 33.5 MB

    const int lds1 = 4*2312*4;                    // 36,992 B (k1)
    const int lds2 = (1728 + 64*100) * 4;         // 32,512 B (k2)
    (void)hipFuncSetAttribute((const void*)k1_offset_conv,
        hipFuncAttributeMaxDynamicSharedMemorySize, lds1);
    (void)hipFuncSetAttribute((const void*)k2_deform,
        hipFuncAttributeMaxDynamicSharedMemorySize, lds2);

    hipLaunchKernelGGL(kTm, dim3(656), dim3(256), 0, stream,
                       f1, f3, ow, mw, f13t, wmf, wof);
    hipLaunchKernelGGL(k1_offset_conv, dim3(1024), dim3(256), lds1, stream,
                       f13t, wof, ob, om);
    hipLaunchKernelGGL(k2_deform, dim3(1024), dim3(512), lds2, stream,
                       f13t, wmf, om, alignedh, part);
    hipLaunchKernelGGL(k3b_reduce, dim3(128), dim3(256), 0, stream, part, stats);
    hipLaunchKernelGGL(k4_norm, dim3(2048), dim3(256), 0, stream,
                       alignedh, stats, gamma, beta, out);
}

// Round 24
// 63.210 us; speedup vs baseline: 1.1499x; 1.1499x over previous
//
#include <hip/hip_runtime.h>
#include <math.h>

#define BB 4
#define CC 64
#define HH 128
#define WW 128
#define HWP 16384

typedef _Float16 h2 __attribute__((ext_vector_type(2)));
typedef _Float16 h4 __attribute__((ext_vector_type(4)));
typedef __fp16  p2 __attribute__((ext_vector_type(2)));   // cvt_pkrtz's return type
typedef float f32x4 __attribute__((ext_vector_type(4)));
union HU { unsigned u; h2 h; p2 p; };
union U2H { uint2 u; h4 h; };
static __device__ __forceinline__ h2 u2h(unsigned x){ HU v; v.u = x; return v.h; }
static __device__ __forceinline__ unsigned h2u(h2 x){ HU v; v.h = x; return v.u; }
static __device__ __forceinline__ unsigned pk2u(float a, float b){
    HU v; v.p = __builtin_amdgcn_cvt_pkrtz(a, b); return v.u;
}

// ---------------- kTm: merged kT (blocks 0..511) + k0 weight-pack (512..655).
__global__ __launch_bounds__(256) void kTm(
    const float* __restrict__ f1, const float* __restrict__ f3,
    const float* __restrict__ ow, const float* __restrict__ mw,
    unsigned* __restrict__ f13t, unsigned* __restrict__ wmf,
    unsigned* __restrict__ wof)
{
    __shared__ float lt[64*129];
    int t = threadIdx.x;
    if (blockIdx.x < 512) {
        int b = blockIdx.x >> 7, y = blockIdx.x & 127;
        unsigned* dst = f13t + ((size_t)((b << 14) + (y << 7)))*64;
        for (int half = 0; half < 2; ++half) {
            const float* src = (half == 0 ? f1 : f3) + (((size_t)b*64) << 14) + (y << 7);
#pragma unroll 4
            for (int i = 0; i < 32; ++i) {
                int idx = i*256 + t; int c = idx >> 7, x = idx & 127;
                lt[c*129 + x] = src[(c << 14) + x];
            }
            __syncthreads();
#pragma unroll 4
            for (int i = 0; i < 16; ++i) {
                int idx = i*256 + t; int x = idx >> 5, cp = idx & 31;
                dst[x*64 + half*32 + cp] = pk2u(lt[(2*cp)*129 + x], lt[(2*cp+1)*129 + x]);
            }
            __syncthreads();
        }
        return;
    }
    int i = (blockIdx.x - 512)*256 + t;
    if (i < 18432) {                           // wmf: 4*64*36*2
        int j   = i & 1;
        int t2  = i >> 1;
        int kb  = t2 % 36;
        int rl  = t2 / 36;
        int l   = rl & 63;
        int r   = rl >> 6;
        int row = l & 15, ksel = l >> 4;
        int och = r*16 + row;
        int P   = kb*8 + ksel*2 + j;           // 0..287
        int kt  = P >> 5;
        int cp  = P & 31;
        float lo = mw[och*576 + (2*cp    )*9 + kt];
        float hi = mw[och*576 + (2*cp + 1)*9 + kt];
        wmf[i] = pk2u(lo, hi);
    } else if (i < 36864) {                    // wof: 2*64*72*2
        int idx = i - 18432;
        int j   = idx & 1;
        int t2  = idx >> 1;
        int kb  = t2 % 72;
        int rl  = t2 / 72;
        int l   = rl & 63;
        int mt  = rl >> 6;
        int row = l & 15, ksel = l >> 4;
        int och = mt*16 + row;
        int P   = kb*8 + ksel*2 + j;           // 0..575
        int kt  = P >> 6;                      // tap 0..8
        int cp  = P & 63;                      // concat pair
        unsigned v = 0;
        if (och < 27) {
            float lo = ow[(och*128 + 2*cp    )*9 + kt];
            float hi = ow[(och*128 + 2*cp + 1)*9 + kt];
            v = pk2u(lo, hi);
        }
        wof[idx] = v;
    }
}

// ---------------- K1: offset conv via MFMA, y-PAIR blocks (R21, unchanged).
__global__ __launch_bounds__(256) void k1_offset_conv(
    const unsigned* __restrict__ f13t, const unsigned* __restrict__ wof,
    const float* __restrict__ ob, float* __restrict__ om)
{
    extern __shared__ unsigned tile[];   // [4 slabs][34][68] = 36,992 B

    int blk0 = blockIdx.x;
    int blk  = ((blk0 & 7) << 7) | (blk0 >> 3);   // bijective (1024 % 8 == 0)
    int xq = blk & 3;
    int yp = (blk >> 2) & 63;
    int b  = blk >> 8;
    int y0r = yp << 1;

    int tid  = threadIdx.x;
    int lane = tid & 63;
    int wv   = tid >> 6;
    int mt   = wv >> 1;          // M-tile (out-ch 16*mt..)
    int ys   = wv & 1;           // row of pair
    int row  = lane & 15;
    int ksel = lane >> 4;

    // stage 4 slabs: rows y0r-1 .. y0r+2
#pragma unroll 1
    for (int s = 0; s < 4; ++s) {
        int yy = y0r + s - 1;
        bool yok = (unsigned)yy < (unsigned)HH;
        unsigned* ts = tile + s*2312;
        for (int i = tid; i < 544; i += 256) {
            int px34 = i >> 4, q = i & 15;
            int gxp = xq*32 - 1 + px34;
            uint4 v = make_uint4(0u, 0u, 0u, 0u);
            if (yok && (unsigned)gxp < (unsigned)WW)
                v = *(const uint4*)&f13t[(((size_t)(b*128 + yy))*128 + gxp)*64 + q*4];
            *(uint4*)&ts[px34*68 + q*4] = v;
        }
    }
    __syncthreads();

    f32x4 acc0 = {0.f, 0.f, 0.f, 0.f};
    f32x4 acc1 = {0.f, 0.f, 0.f, 0.f};
    const unsigned* wbase = wof + (size_t)(mt*64 + lane)*144;

#pragma unroll 1
    for (int dy = 0; dy < 3; ++dy) {
        const unsigned* ts = tile + (ys + dy)*2312;
#pragma unroll
        for (int hf = 0; hf < 2; ++hf) {
            uint4 wq[6];
#pragma unroll
            for (int m = 0; m < 6; ++m)
                wq[m] = *(const uint4*)&wbase[dy*48 + hf*24 + m*4];
#pragma unroll
            for (int kl = 0; kl < 12; ++kl) {
                int Pl  = (hf*12 + kl)*8 + ksel*2;
                int ktl = Pl >> 6;
                int cp  = Pl & 63;
                U2H wa;
                uint4 q = wq[kl >> 1];
                if (kl & 1) { wa.u.x = q.z; wa.u.y = q.w; }
                else        { wa.u.x = q.x; wa.u.y = q.y; }
                U2H b0, b1;
                b0.u = *(const uint2*)&ts[(row + ktl)*68 + cp];
                b1.u = *(const uint2*)&ts[(16 + row + ktl)*68 + cp];
                acc0 = __builtin_amdgcn_mfma_f32_16x16x16f16(wa.h, b0.h, acc0, 0, 0, 0);
                acc1 = __builtin_amdgcn_mfma_f32_16x16x16f16(wa.h, b1.h, acc1, 0, 0, 0);
            }
        }
    }

    int y  = y0r + ys;
    int gx0 = xq*32 + row;
#pragma unroll
    for (int rI = 0; rI < 4; ++rI) {
        int och = mt*16 + ksel*4 + rI;
        if (och < 27) {
            float v0 = acc0[rI] + ob[och];
            float v1 = acc1[rI] + ob[och];
            if (och >= 18) {
                v0 = 1.f / (1.f + __expf(-v0));   // mask sigmoid
                v1 = 1.f / (1.f + __expf(-v1));
            }
            int base = ((b*27 + och) << 14) + (y << 7) + gx0;
            om[base]      = v0;
            om[base + 16] = v1;
        }
    }
}

// ---------------- K2: deformable conv, HALF-ROW blocks (64 px, grid 1024),
// 256 threads (R22 proven body — R23's 512-thread variant regressed: halved
// per-wave phase-A ILP + wider barrier convoy).
// LDS: params 1728 + sl[64][100] = 32,512 B -> 4 blocks/CU single pass.
__global__ __launch_bounds__(256) void k2_deform(
    const unsigned* __restrict__ f13t, const unsigned* __restrict__ wmf,
    const float* __restrict__ om, unsigned* __restrict__ alignedh,
    float* __restrict__ part)
{
    extern __shared__ unsigned lds[];
    unsigned* pl_a = lds;            // [9][64] addr|dx<<14|dy<<15
    unsigned* pl_w = lds + 576;      // [9][64] x uint2
    unsigned* sl   = lds + 1728;     // [64 px][100] permuted half2 samples

    int blk0 = blockIdx.x;
    int blk  = ((blk0 & 7) << 7) | (blk0 >> 3);   // bijective (1024 % 8 == 0)
    int xh = blk & 1;
    int y  = (blk >> 1) & 127;
    int b  = blk >> 8;

    int tid  = threadIdx.x;
    int lane = tid & 63;
    int wv   = tid >> 6;
    int row  = lane & 15;
    int ksel = lane >> 4;
    int cg   = tid & 7;          // phase-A channel group (4 pairs: 4cg..4cg+3)
    int grp  = tid >> 3;         // phase-A item group 0..31
    int pwb  = ((cg >> 2) << 4) | ((cg & 1) << 3) | (((cg >> 1) & 1) << 1);

    const float* omb = om + ((b*27) << 14) + (y << 7);
    const unsigned* ftb = f13t + (((size_t)b) << 20);

    // ---- param pre-phase: 576 items (k, px in half-row)
    for (int i = tid; i < 576; i += 256) {
        int k = i >> 6, lpx = i & 63;
        int gxp = xh*64 + lpx;
        float off0 = omb[((2*k)   << 14) + gxp];
        float off1 = omb[((2*k+1) << 14) + gxp];
        float mk   = omb[((18+k)  << 14) + gxp];   // sigmoided in K1

        float pyf = (float)y   + (float)(k/3) - 1.f + off0;
        float pxg = (float)gxp + (float)(k%3) - 1.f + off1;
        float fy = floorf(pyf), fx = floorf(pxg);
        int y0 = (int)fy, x0 = (int)fx;
        float wy = pyf - fy, wx = pxg - fx;
        float oy = 1.f - wy, ox = 1.f - wx;
        bool yv0 = (unsigned)y0     < (unsigned)HH;
        bool yv1 = (unsigned)(y0+1) < (unsigned)HH;
        bool xv0 = (unsigned)x0     < (unsigned)WW;
        bool xv1 = (unsigned)(x0+1) < (unsigned)WW;
        int y0c = min(max(y0, 0), 127);
        int x0c = min(max(x0, 0), 127);
        int dy = min(max(y0+1, 0), 127) - y0c;   // 0 or 1
        int dx = min(max(x0+1, 0), 127) - x0c;   // 0 or 1
        unsigned a = (unsigned)((y0c << 7) + x0c) | ((unsigned)dx << 14) | ((unsigned)dy << 15);
        float w00 = (yv0 && xv0) ? oy*ox*mk : 0.f;
        float w01 = (yv0 && xv1) ? oy*wx*mk : 0.f;
        float w10 = (yv1 && xv0) ? wy*ox*mk : 0.f;
        float w11 = (yv1 && xv1) ? wy*wx*mk : 0.f;
        pl_a[i] = a;
        pl_w[i*2]     = pk2u(w00, w01);
        pl_w[i*2 + 1] = pk2u(w10, w11);
    }
    __syncthreads();

    f32x4 accA = {0.f,0.f,0.f,0.f};   // px-tile 0 (px = row)
    f32x4 accB = {0.f,0.f,0.f,0.f};   // px-tile 1 (px = 16+row)
    f32x4 accC = {0.f,0.f,0.f,0.f};   // px-tile 2
    f32x4 accD = {0.f,0.f,0.f,0.f};   // px-tile 3

    const unsigned* wbase = wmf + (wv*64 + lane)*72;

#pragma unroll 1
    for (int th = 0; th < 3; ++th) {
        uint4 wq[6];
#pragma unroll
        for (int m = 0; m < 6; ++m)
            wq[m] = *(const uint4*)&wbase[th*24 + m*4];

        // phase A: 192 items (ktl,px); 8-lane group = one item, 6/group
#pragma unroll 3
        for (int it = 0; it < 6; ++it) {
            int item = it*32 + grp;            // 0..191
            int ktl  = item >> 6;              // 0..2
            int px   = item & 63;
            int k    = th*3 + ktl;
            int pidx = k*64 + px;
            unsigned a = pl_a[pidx];
            uint2 wpk = *(const uint2*)&pl_w[pidx*2];
            int i00 = (int)(a & 0x3FFFu);
            int dx  = (int)((a >> 14) & 1u);
            int i10 = i00 + (((int)(a >> 15) & 1) << 7);
            h2 hw01 = u2h(wpk.x);
            h2 hw23 = u2h(wpk.y);
            h2 w00d = {hw01.x, hw01.x}, w01d = {hw01.y, hw01.y};
            h2 w10d = {hw23.x, hw23.x}, w11d = {hw23.y, hw23.y};

            uint4 t00 = *(const uint4*)&ftb[(size_t)(i00     )*64 + 4*cg];
            uint4 t01 = *(const uint4*)&ftb[(size_t)(i00 + dx)*64 + 4*cg];
            uint4 t10 = *(const uint4*)&ftb[(size_t)(i10     )*64 + 4*cg];
            uint4 t11 = *(const uint4*)&ftb[(size_t)(i10 + dx)*64 + 4*cg];

            h2 v0 = u2h(t00.x)*w00d + u2h(t01.x)*w01d + u2h(t10.x)*w10d + u2h(t11.x)*w11d;
            h2 v1 = u2h(t00.y)*w00d + u2h(t01.y)*w01d + u2h(t10.y)*w10d + u2h(t11.y)*w11d;
            h2 v2 = u2h(t00.z)*w00d + u2h(t01.z)*w01d + u2h(t10.z)*w10d + u2h(t11.z)*w11d;
            h2 v3 = u2h(t00.w)*w00d + u2h(t01.w)*w01d + u2h(t10.w)*w10d + u2h(t11.w)*w11d;

            int bs = px*100 + ktl*32 + pwb;
            *(uint2*)&sl[bs]     = make_uint2(h2u(v0), h2u(v1));
            *(uint2*)&sl[bs + 4] = make_uint2(h2u(v2), h2u(v3));
        }
        __syncthreads();

        // phase B: 6 double-K-blocks x 4 px-tiles, ds_read_b128
        const unsigned* bpA = &sl[(row     )*100 + ksel*4];
        const unsigned* bpB = &sl[(16+row  )*100 + ksel*4];
        const unsigned* bpC = &sl[(32+row  )*100 + ksel*4];
        const unsigned* bpD = &sl[(48+row  )*100 + ksel*4];
#pragma unroll
        for (int m = 0; m < 6; ++m) {
            uint4 bvA = *(const uint4*)&bpA[m*16];
            uint4 bvB = *(const uint4*)&bpB[m*16];
            uint4 bvC = *(const uint4*)&bpC[m*16];
            uint4 bvD = *(const uint4*)&bpD[m*16];
            U2H waA, waB, sa, sb;
            waA.u.x = wq[m].x; waA.u.y = wq[m].y;
            waB.u.x = wq[m].z; waB.u.y = wq[m].w;
            sa.u.x = bvA.x; sa.u.y = bvA.y;
            sb.u.x = bvA.z; sb.u.y = bvA.w;
            accA = __builtin_amdgcn_mfma_f32_16x16x16f16(waA.h, sa.h, accA, 0, 0, 0);
            accA = __builtin_amdgcn_mfma_f32_16x16x16f16(waB.h, sb.h, accA, 0, 0, 0);
            sa.u.x = bvB.x; sa.u.y = bvB.y;
            sb.u.x = bvB.z; sb.u.y = bvB.w;
            accB = __builtin_amdgcn_mfma_f32_16x16x16f16(waA.h, sa.h, accB, 0, 0, 0);
            accB = __builtin_amdgcn_mfma_f32_16x16x16f16(waB.h, sb.h, accB, 0, 0, 0);
            sa.u.x = bvC.x; sa.u.y = bvC.y;
            sb.u.x = bvC.z; sb.u.y = bvC.w;
            accC = __builtin_amdgcn_mfma_f32_16x16x16f16(waA.h, sa.h, accC, 0, 0, 0);
            accC = __builtin_amdgcn_mfma_f32_16x16x16f16(waB.h, sb.h, accC, 0, 0, 0);
            sa.u.x = bvD.x; sa.u.y = bvD.y;
            sb.u.x = bvD.z; sb.u.y = bvD.w;
            accD = __builtin_amdgcn_mfma_f32_16x16x16f16(waA.h, sa.h, accD, 0, 0, 0);
            accD = __builtin_amdgcn_mfma_f32_16x16x16f16(waB.h, sb.h, accD, 0, 0, 0);
        }
        __syncthreads();
    }

    // write aligned (packed f16 pairs) + per-block stats partials
    float* sred = (float*)lds;   // reuse (safe: past last barrier)
#pragma unroll
    for (int rI = 0; rI < 4; ++rI) {
        int och = wv*16 + ksel*4 + rI;
        float v0 = accA[rI], v1 = accB[rI], v2 = accC[rI], v3 = accD[rI];
        int ai = (((b*CC + och) << 13)) + (y << 6) + row;
        alignedh[ai + ((2*xh    ) << 4)] = pk2u(v0, v1);
        alignedh[ai + ((2*xh + 1) << 4)] = pk2u(v2, v3);
        float s  = v0 + v1 + v2 + v3;
        float sq = v0*v0 + v1*v1 + v2*v2 + v3*v3;
#pragma unroll
        for (int off = 1; off < 16; off <<= 1) {
            s  += __shfl_xor(s,  off, 64);
            sq += __shfl_xor(sq, off, 64);
        }
        if (row == 0) { sred[och] = s; sred[64 + och] = sq; }
    }
    __syncthreads();
    for (int i = tid; i < 128; i += 256)
        part[(size_t)blk*128 + i] = sred[i];
}

// ---------------- K3b: reduce 1024 per-block partials -> stats[128]
__global__ __launch_bounds__(256) void k3b_reduce(
    const float* __restrict__ part, float* __restrict__ stats)
{
    int i = blockIdx.x;           // 0..127
    int tid = threadIdx.x;
    float s = 0.f;
    for (int j = tid; j < 1024; j += 256) s += part[(size_t)j*128 + i];
    for (int off = 32; off > 0; off >>= 1) s += __shfl_down(s, off, 64);
    __shared__ float rs[4];
    int w = tid >> 6;
    if ((tid & 63) == 0) rs[w] = s;
    __syncthreads();
    if (tid == 0) stats[i] = rs[0] + rs[1] + rs[2] + rs[3];
}

// ---------------- K4: normalize + affine, f16-packed input -> f32 out.
__global__ __launch_bounds__(256) void k4_norm(
    const unsigned* __restrict__ alignedh, const float* __restrict__ stats,
    const float* __restrict__ gamma, const float* __restrict__ beta,
    float* __restrict__ out)
{
    const float invN = 1.f / 65536.f;
    int i4 = blockIdx.x*256 + threadIdx.x;     // 0..524287
    int u  = i4 << 2;
    int c  = (u >> 13) & 63;
    int lx = u & 15;
    int xq = (u >> 4) & 3;
    int y  = (u >> 6) & 127;
    int bc = u >> 13;                          // b*64 + c

    float mean = stats[c] * invN;
    float var  = stats[64 + c] * invN - mean*mean;
    float sc = gamma[c] * rsqrtf(var + 1e-5f);
    float sh = beta[c] - mean*sc;

    uint4 v = *(const uint4*)&alignedh[u];
    h2 p0 = u2h(v.x), p1 = u2h(v.y), p2 = u2h(v.z), p3 = u2h(v.w);
    float4 lo = make_float4((float)p0.x*sc + sh, (float)p1.x*sc + sh,
                            (float)p2.x*sc + sh, (float)p3.x*sc + sh);
    float4 hi = make_float4((float)p0.y*sc + sh, (float)p1.y*sc + sh,
                            (float)p2.y*sc + sh, (float)p3.y*sc + sh);
    int ob = (bc << 14) + (y << 7) + xq*32 + lx;
    *(float4*)&out[ob]      = lo;
    *(float4*)&out[ob + 16] = hi;
}

extern "C" void kernel_launch(void* const* d_in, const int* in_sizes, int n_in,
                              void* d_out, int out_size, void* d_ws, size_t ws_size,
                              hipStream_t stream)
{
    const float* f1    = (const float*)d_in[0];
    const float* f3    = (const float*)d_in[1];
    const float* ow    = (const float*)d_in[2];
    const float* ob    = (const float*)d_in[3];
    const float* mw    = (const float*)d_in[4];
    const float* gamma = (const float*)d_in[5];
    const float* beta  = (const float*)d_in[6];
    float* out = (float*)d_out;

    float* om     = (float*)d_ws;                 // [4][27][128][128] = 7,077,888 B
    float* stats  = om + 4*27*HWP;                // [128] floats (512 reserved)
    unsigned* wmf = (unsigned*)(stats + 512);     // 18432 u32
    unsigned* wof = wmf + 18432;                  // 18432 u32
    unsigned* f13t = wof + 18432;                 // [4][128][128][64] u32 = 16 MB
    float* part   = (float*)(f13t + 4*HWP*64);    // [1024][128] floats
    unsigned* alignedh = (unsigned*)(part + 2048*128);  // [4][64][128][64] u32 = 33.5 MB

    const int lds1 = 4*2312*4;                    // 36,992 B (k1)
    const int lds2 = (1728 + 64*100) * 4;         // 32,512 B (k2)
    (void)hipFuncSetAttribute((const void*)k1_offset_conv,
        hipFuncAttributeMaxDynamicSharedMemorySize, lds1);
    (void)hipFuncSetAttribute((const void*)k2_deform,
        hipFuncAttributeMaxDynamicSharedMemorySize, lds2);

    hipLaunchKernelGGL(kTm, dim3(656), dim3(256), 0, stream,
                       f1, f3, ow, mw, f13t, wmf, wof);
    hipLaunchKernelGGL(k1_offset_conv, dim3(1024), dim3(256), lds1, stream,
                       f13t, wof, ob, om);
    hipLaunchKernelGGL(k2_deform, dim3(1024), dim3(256), lds2, stream,
                       f13t, wmf, om, alignedh, part);
    hipLaunchKernelGGL(k3b_reduce, dim3(128), dim3(256), 0, stream, part, stats);
    hipLaunchKernelGGL(k4_norm, dim3(2048), dim3(256), 0, stream,
                       alignedh, stats, gamma, beta, out);
}